// Round 2
// baseline (734.761 us; speedup 1.0000x reference)
//
#include <hip/hip_runtime.h>
#include <hip/hip_bf16.h>
#include <cstdint>

// Problem constants
static constexpr int Bc  = 4;
static constexpr int Sc  = 8192;
static constexpr int Dc  = 1024;
static constexpr int Hc  = 16;
static constexpr int HDc = 64;
static constexpr int ADc = 64;
static constexpr int BHc = Bc * Hc;   // 64
static constexpr int Mc  = Bc * Sc;   // 32768
static constexpr int N3c = 3 * Dc;    // 3072
static constexpr float EPSc = 1e-6f;

using bf16x8 = __attribute__((ext_vector_type(8))) __bf16;
using f32x4  = __attribute__((ext_vector_type(4))) float;

__device__ __forceinline__ ushort f2bf(float f) {
  union { float f; uint32_t u; } v; v.f = f;
  uint32_t u = v.u;
  return (ushort)((u + 0x7fffu + ((u >> 16) & 1u)) >> 16);  // RNE
}
__device__ __forceinline__ float bf2f(ushort h) {
  union { uint32_t u; float f; } v; v.u = ((uint32_t)h) << 16;
  return v.f;
}

typedef const __attribute__((address_space(1))) unsigned int* gas_u32p;
typedef __attribute__((address_space(3))) unsigned int* las_u32p;
__device__ __forceinline__ void gld_lds16(const void* g, void* l) {
  __builtin_amdgcn_global_load_lds((gas_u32p)g, (las_u32p)l, 16, 0, 0);
}

// ---------------------------------------------------------------- kernel 0: fp32 -> bf16 convert
__global__ __launch_bounds__(256) void cvt_bf16_k(const float* __restrict__ src,
                                                  ushort* __restrict__ dst, int n4) {
  int i = blockIdx.x * 256 + threadIdx.x;
  if (i < n4) {
    float4 v = reinterpret_cast<const float4*>(src)[i];
    ushort4 o; o.x = f2bf(v.x); o.y = f2bf(v.y); o.z = f2bf(v.z); o.w = f2bf(v.w);
    reinterpret_cast<ushort4*>(dst)[i] = o;
  }
}

// ---------------------------------------------------------------- kernel 1: QKV GEMM + fused phi
// C[m,n] = dot(xb[m,:], W3b[n,:]) + b[n].  For Q/K parts additionally computes
// phi = sqrt(1 + (C_head . W_p^T + b_p)^2) per head (HD=64 == one wave's N-span).
// Writes phiQ / phiK / V in [B,H,S,64] bf16 layout.
__global__ __launch_bounds__(256) void qkv_fused_k(const ushort* __restrict__ xb,
                                                   const ushort* __restrict__ W3b,
                                                   const float* __restrict__ bqkv,
                                                   const ushort* __restrict__ Wpb,
                                                   const float* __restrict__ bp,
                                                   ushort* __restrict__ Qb,
                                                   ushort* __restrict__ Kb,
                                                   ushort* __restrict__ Vb) {
  // union: staging As[128][64]+Bs[128][64] (32 KB) OR epilogue Ep[4][64][80] (40 KB)
  __shared__ __align__(16) char smem[40960];
  ushort* As = (ushort*)smem;              // linear [128][64] (global_load_lds dest)
  ushort* Bs = (ushort*)(smem + 16384);    // linear [128][64]
  const int t = threadIdx.x, wave = t >> 6, lane = t & 63;
  const int lr = lane & 15, kg = lane >> 4;
  const int wm = wave >> 1, wn = wave & 1;

  // XCD-bijective swizzle: nwg = 6144 = 8 * 768; each XCD gets 32 M-rows x 24 N contiguous.
  const int flat = blockIdx.y * 24 + blockIdx.x;
  const int swz  = (flat & 7) * 768 + (flat >> 3);
  const int n0 = (swz % 24) * 128;
  const int m0 = (swz / 24) * 128;

  f32x4 acc[4][4];
#pragma unroll
  for (int i = 0; i < 4; i++)
#pragma unroll
    for (int j = 0; j < 4; j++) acc[i][j] = (f32x4){0.f, 0.f, 0.f, 0.f};

  const int srow = lane >> 3;           // row within 8-row chunk
  const int scol = (lane & 7) * 8;      // bf16 col within 64
  for (int kt = 0; kt < 1024; kt += 64) {
    __syncthreads();
    // stage A(x) and B(W) tiles: 16 KB each, 4 x 1KB wave-instructions per wave per tile
#pragma unroll
    for (int i = 0; i < 4; i++) {
      const int c = wave * 4 + i;            // chunk: rows c*8..c*8+7
      gld_lds16(&xb [(size_t)(m0 + c * 8 + srow) * 1024 + kt + scol], As + c * 512);
      gld_lds16(&W3b[(size_t)(n0 + c * 8 + srow) * 1024 + kt + scol], Bs + c * 512);
    }
    __syncthreads();
#pragma unroll
    for (int ks = 0; ks < 64; ks += 32) {
      bf16x8 af[4], bfr[4];
#pragma unroll
      for (int i = 0; i < 4; i++)
        af[i] = *reinterpret_cast<const bf16x8*>(As + (wm * 64 + i * 16 + lr) * 64 + ks + kg * 8);
#pragma unroll
      for (int j = 0; j < 4; j++)
        bfr[j] = *reinterpret_cast<const bf16x8*>(Bs + (wn * 64 + j * 16 + lr) * 64 + ks + kg * 8);
#pragma unroll
      for (int i = 0; i < 4; i++)
#pragma unroll
        for (int j = 0; j < 4; j++)
          acc[i][j] = __builtin_amdgcn_mfma_f32_16x16x32_bf16(af[i], bfr[j], acc[i][j], 0, 0, 0);
    }
  }
  __syncthreads();   // all As/Bs reads done before Ep reuse

  // epilogue: this wave's 64 cols = one full head of one part (block-uniform part)
  const int n0w  = n0 + wn * 64;
  const int part = n0 >> 10;              // 0=Q 1=K 2=V  (block-uniform)
  const int h    = (n0w & 1023) >> 6;
  ushort* dst = (part == 0) ? Qb : (part == 1 ? Kb : Vb);
  const int bq     = m0 >> 13;
  const int s_base = (m0 & 8191) + wm * 64;
  const size_t hb  = ((size_t)(bq * Hc + h)) * Sc * 64;
  float bias[4];
#pragma unroll
  for (int j = 0; j < 4; j++) bias[j] = bqkv[n0w + j * 16 + lr];

  if (part == 2) {
    // V: bias + cvt + store
#pragma unroll
    for (int j = 0; j < 4; j++)
#pragma unroll
      for (int i = 0; i < 4; i++)
#pragma unroll
        for (int r = 0; r < 4; r++)
          dst[hb + (size_t)(s_base + i * 16 + kg * 4 + r) * 64 + j * 16 + lr] =
              f2bf(acc[i][j][r] + bias[j]);
  } else {
    // Q/K: transpose tile through per-wave LDS region, project with W_p, apply phi
    ushort* ep = (ushort*)smem + wave * 5120;   // [64][80] bf16, 10240 B per wave
#pragma unroll
    for (int j = 0; j < 4; j++)
#pragma unroll
      for (int i = 0; i < 4; i++)
#pragma unroll
        for (int r = 0; r < 4; r++)
          ep[(i * 16 + kg * 4 + r) * 80 + j * 16 + lr] = f2bf(acc[i][j][r] + bias[j]);
    // per-wave-private region: in-wave ds ordering + compiler waits suffice

    f32x4 pacc[4][4];
#pragma unroll
    for (int i = 0; i < 4; i++)
#pragma unroll
      for (int j = 0; j < 4; j++) pacc[i][j] = (f32x4){0.f, 0.f, 0.f, 0.f};
#pragma unroll
    for (int ks2 = 0; ks2 < 2; ks2++) {
      bf16x8 af2[4], wf[4];
#pragma unroll
      for (int i = 0; i < 4; i++)
        af2[i] = *reinterpret_cast<const bf16x8*>(&ep[(i * 16 + lr) * 80 + ks2 * 32 + kg * 8]);
#pragma unroll
      for (int j = 0; j < 4; j++)
        wf[j] = *reinterpret_cast<const bf16x8*>(&Wpb[(j * 16 + lr) * 64 + ks2 * 32 + kg * 8]);
#pragma unroll
      for (int i = 0; i < 4; i++)
#pragma unroll
        for (int j = 0; j < 4; j++)
          pacc[i][j] = __builtin_amdgcn_mfma_f32_16x16x32_bf16(af2[i], wf[j], pacc[i][j], 0, 0, 0);
    }
#pragma unroll
    for (int j = 0; j < 4; j++) {
      float bpj = bp[j * 16 + lr];
#pragma unroll
      for (int i = 0; i < 4; i++)
#pragma unroll
        for (int r = 0; r < 4; r++) {
          float p = pacc[i][j][r] + bpj;
          dst[hb + (size_t)(s_base + i * 16 + kg * 4 + r) * 64 + j * 16 + lr] =
              f2bf(sqrtf(1.f + p * p));
        }
    }
  }
}

// ---------------------------------------------------------------- kernel 3: per-chunk KTV partials + ksum partials
__global__ __launch_bounds__(256) void ktv_part_k(const ushort* __restrict__ Kphi,
                                                  const ushort* __restrict__ Vb,
                                                  float* __restrict__ KTVp,
                                                  float* __restrict__ ksump) {
  __shared__ ushort KsT[64][136];   // [a][s]  (transposed)
  __shared__ ushort VsT[64][136];   // [v][s]
  __shared__ float  red[64][65];
  const int t = threadIdx.x;
  const int chunk = blockIdx.x, bh = blockIdx.y;
  const int wave = t >> 6, lane = t & 63, lr = lane & 15, kg = lane >> 4;
  const size_t hb = (size_t)bh * Sc * 64;

  f32x4 acc[4][4];
#pragma unroll
  for (int i = 0; i < 4; i++)
#pragma unroll
    for (int j = 0; j < 4; j++) acc[i][j] = (f32x4){0.f, 0.f, 0.f, 0.f};
  float ks_acc = 0.f;

  for (int sub = 0; sub < 4; sub++) {
    const int sb = chunk * 512 + sub * 128;
    __syncthreads();
#pragma unroll
    for (int i = 0; i < 8; i++) {
      int li = i * 256 + t;              // ushort4 units
      int s = li >> 4, a4 = (li & 15) * 4;
      ushort4 kv = *reinterpret_cast<const ushort4*>(&Kphi[hb + (size_t)(sb + s) * 64 + a4]);
      ushort4 vv = *reinterpret_cast<const ushort4*>(&Vb[hb + (size_t)(sb + s) * 64 + a4]);
      KsT[a4 + 0][s] = kv.x; KsT[a4 + 1][s] = kv.y; KsT[a4 + 2][s] = kv.z; KsT[a4 + 3][s] = kv.w;
      VsT[a4 + 0][s] = vv.x; VsT[a4 + 1][s] = vv.y; VsT[a4 + 2][s] = vv.z; VsT[a4 + 3][s] = vv.w;
    }
    __syncthreads();
    {
      const int ko = wave * 32 + kg * 8;   // waves split the 128-deep K range
      bf16x8 af[4], bfr[4];
#pragma unroll
      for (int i = 0; i < 4; i++)
        af[i] = *reinterpret_cast<const bf16x8*>(&KsT[i * 16 + lr][ko]);
#pragma unroll
      for (int j = 0; j < 4; j++)
        bfr[j] = *reinterpret_cast<const bf16x8*>(&VsT[j * 16 + lr][ko]);
#pragma unroll
      for (int i = 0; i < 4; i++)
#pragma unroll
        for (int j = 0; j < 4; j++)
          acc[i][j] = __builtin_amdgcn_mfma_f32_16x16x32_bf16(af[i], bfr[j], acc[i][j], 0, 0, 0);
    }
    if (t < 64) {
      float s = 0.f;
      for (int ss = 0; ss < 128; ss++) s += bf2f(KsT[t][ss]);
      ks_acc += s;
    }
  }

  __syncthreads();
  for (int li = t; li < 64 * 65; li += 256) (&red[0][0])[li] = 0.f;
  __syncthreads();
  for (int w = 0; w < 4; w++) {
    if (wave == w) {
#pragma unroll
      for (int i = 0; i < 4; i++)
#pragma unroll
        for (int j = 0; j < 4; j++)
#pragma unroll
          for (int r = 0; r < 4; r++)
            red[i * 16 + kg * 4 + r][j * 16 + lr] += acc[i][j][r];
    }
    __syncthreads();
  }
  float* outp = KTVp + ((size_t)bh * 16 + chunk) * 4096;
  for (int li = t; li < 4096; li += 256) outp[li] = red[li >> 6][li & 63];
  if (t < 64) ksump[((size_t)bh * 16 + chunk) * 64 + t] = ks_acc;
}

// ---------------------------------------------------------------- kernel 3b: reduce partials
__global__ __launch_bounds__(256) void ktv_red_k(const float* __restrict__ KTVp,
                                                 const float* __restrict__ ksump,
                                                 float* __restrict__ KTV,
                                                 float* __restrict__ ksum) {
  const int bh = blockIdx.x, t = threadIdx.x;
  for (int li = t; li < 4096; li += 256) {
    float s = 0.f;
    for (int c = 0; c < 16; c++) s += KTVp[((size_t)bh * 16 + c) * 4096 + li];
    KTV[(size_t)bh * 4096 + li] = s;
  }
  if (t < 64) {
    float s = 0.f;
    for (int c = 0; c < 16; c++) s += ksump[((size_t)bh * 16 + c) * 64 + t];
    ksum[bh * 64 + t] = s;
  }
}

// ---------------------------------------------------------------- kernel 4: numerator + denominator + output
__global__ __launch_bounds__(256) void out_k(const ushort* __restrict__ Qphi,
                                             const float* __restrict__ KTV,
                                             const float* __restrict__ ksum,
                                             float* __restrict__ out) {
  __shared__ ushort Qs[256][72];
  __shared__ ushort BT[64][72];     // KTV^T in bf16: BT[v][a]
  __shared__ float  den[256];
  __shared__ float  kss[64];
  const int t = threadIdx.x;
  const int bh = blockIdx.y, s0 = blockIdx.x * 256;
  const ushort* qb = Qphi + (size_t)bh * Sc * 64 + (size_t)s0 * 64;

#pragma unroll
  for (int i = 0; i < 8; i++) {
    int li = i * 256 + t;
    int r = li >> 3, c8 = li & 7;
    *reinterpret_cast<uint4*>(&Qs[r][c8 * 8]) = *reinterpret_cast<const uint4*>(&qb[li * 8]);
  }
  for (int li = t; li < 4096; li += 256) {
    int a = li >> 6, v = li & 63;
    BT[v][a] = f2bf(KTV[(size_t)bh * 4096 + li]);
  }
  if (t < 64) kss[t] = ksum[bh * 64 + t];
  __syncthreads();

  {
    float d = 0.f;
    for (int a = 0; a < 64; a++) d += bf2f(Qs[t][a]) * kss[a];
    den[t] = d + EPSc;
  }
  __syncthreads();

  const int wave = t >> 6, lane = t & 63, lr = lane & 15, kg = lane >> 4;
  f32x4 acc[4][4];
#pragma unroll
  for (int i = 0; i < 4; i++)
#pragma unroll
    for (int j = 0; j < 4; j++) acc[i][j] = (f32x4){0.f, 0.f, 0.f, 0.f};

#pragma unroll
  for (int ks = 0; ks < 64; ks += 32) {
    bf16x8 af[4], bfr[4];
#pragma unroll
    for (int i = 0; i < 4; i++)
      af[i] = *reinterpret_cast<const bf16x8*>(&Qs[wave * 64 + i * 16 + lr][ks + kg * 8]);
#pragma unroll
    for (int j = 0; j < 4; j++)
      bfr[j] = *reinterpret_cast<const bf16x8*>(&BT[j * 16 + lr][ks + kg * 8]);
#pragma unroll
    for (int i = 0; i < 4; i++)
#pragma unroll
      for (int j = 0; j < 4; j++)
        acc[i][j] = __builtin_amdgcn_mfma_f32_16x16x32_bf16(af[i], bfr[j], acc[i][j], 0, 0, 0);
  }

  const int bq = bh >> 4, h = bh & 15;
#pragma unroll
  for (int i = 0; i < 4; i++) {
#pragma unroll
    for (int j = 0; j < 4; j++) {
#pragma unroll
      for (int r = 0; r < 4; r++) {
        int row = wave * 64 + i * 16 + kg * 4 + r;
        int s = s0 + row;
        int v = j * 16 + lr;
        out[((size_t)bq * Sc + s) * 1024 + h * 64 + v] = acc[i][j][r] / den[row];
      }
    }
  }
}

// ---------------------------------------------------------------- launch
extern "C" void kernel_launch(void* const* d_in, const int* in_sizes, int n_in,
                              void* d_out, int out_size, void* d_ws, size_t ws_size,
                              hipStream_t stream) {
  const float* x     = (const float*)d_in[0];
  const float* W_qkv = (const float*)d_in[1];
  const float* b_qkv = (const float*)d_in[2];
  const float* W_p   = (const float*)d_in[3];
  const float* b_p   = (const float*)d_in[4];
  float* out = (float*)d_out;

  size_t off = 0;
  auto carve = [&](size_t bytes) -> void* {
    void* p = (char*)d_ws + off;
    off += (bytes + 255) & ~(size_t)255;
    return p;
  };
  const size_t headElems = (size_t)BHc * Sc * 64;           // 33,554,432
  ushort* xb   = (ushort*)carve((size_t)Mc * Dc * 2);       // 64 MB bf16 x
  ushort* Qb   = (ushort*)carve(headElems * 2);             // phiQ
  ushort* Kb   = (ushort*)carve(headElems * 2);             // phiK
  ushort* Vb   = (ushort*)carve(headElems * 2);
  ushort* W3b  = (ushort*)carve((size_t)N3c * Dc * 2);
  ushort* Wpb  = (ushort*)carve((size_t)ADc * HDc * 2);
  float*  KTVp = (float*)carve((size_t)BHc * 16 * 4096 * 4);
  float*  ksmp = (float*)carve((size_t)BHc * 16 * 64 * 4);
  float*  KTV  = (float*)carve((size_t)BHc * 4096 * 4);
  float*  ksum = (float*)carve((size_t)BHc * 64 * 4);
  (void)ws_size; (void)n_in; (void)in_sizes; (void)out_size;

  // 0: convert inputs to bf16
  cvt_bf16_k<<<(Mc * Dc / 4 + 255) / 256, 256, 0, stream>>>(x, xb, Mc * Dc / 4);
  cvt_bf16_k<<<(N3c * Dc / 4 + 255) / 256, 256, 0, stream>>>(W_qkv, W3b, N3c * Dc / 4);
  cvt_bf16_k<<<(ADc * HDc / 4 + 255) / 256, 256, 0, stream>>>(W_p, Wpb, ADc * HDc / 4);
  // 1: QKV GEMM + fused phi -> phiQ / phiK / V
  qkv_fused_k<<<dim3(N3c / 128, Mc / 128), 256, 0, stream>>>(xb, W3b, b_qkv, Wpb, b_p,
                                                             Qb, Kb, Vb);
  // 3: KTV + ksum partials, then reduce
  ktv_part_k<<<dim3(16, BHc), 256, 0, stream>>>(Kb, Vb, KTVp, ksmp);
  ktv_red_k<<<BHc, 256, 0, stream>>>(KTVp, ksmp, KTV, ksum);
  // 4: output
  out_k<<<dim3(Sc / 256, BHc), 256, 0, stream>>>(Qb, KTV, ksum, out);
}

// Round 3
// 544.657 us; speedup vs baseline: 1.3490x; 1.3490x over previous
//
#include <hip/hip_runtime.h>
#include <hip/hip_bf16.h>
#include <cstdint>

// Problem constants
static constexpr int Bc  = 4;
static constexpr int Sc  = 8192;
static constexpr int Dc  = 1024;
static constexpr int Hc  = 16;
static constexpr int HDc = 64;
static constexpr int ADc = 64;
static constexpr int BHc = Bc * Hc;   // 64
static constexpr int Mc  = Bc * Sc;   // 32768
static constexpr int N3c = 3 * Dc;    // 3072
static constexpr float EPSc = 1e-6f;

using bf16x8 = __attribute__((ext_vector_type(8))) __bf16;
using f32x4  = __attribute__((ext_vector_type(4))) float;

__device__ __forceinline__ ushort f2bf(float f) {
  union { float f; uint32_t u; } v; v.f = f;
  uint32_t u = v.u;
  return (ushort)((u + 0x7fffu + ((u >> 16) & 1u)) >> 16);  // RNE
}
__device__ __forceinline__ float bf2f(ushort h) {
  union { uint32_t u; float f; } v; v.u = ((uint32_t)h) << 16;
  return v.f;
}

typedef const __attribute__((address_space(1))) unsigned int* gas_u32p;
typedef __attribute__((address_space(3))) unsigned int* las_u32p;
__device__ __forceinline__ void gld_lds16(const void* g, void* l) {
  __builtin_amdgcn_global_load_lds((gas_u32p)g, (las_u32p)l, 16, 0, 0);
}

// ---------------------------------------------------------------- kernel 0: fp32 -> bf16 convert
__global__ __launch_bounds__(256) void cvt_bf16_k(const float* __restrict__ src,
                                                  ushort* __restrict__ dst, int n4) {
  int i = blockIdx.x * 256 + threadIdx.x;
  if (i < n4) {
    float4 v = reinterpret_cast<const float4*>(src)[i];
    ushort4 o; o.x = f2bf(v.x); o.y = f2bf(v.y); o.z = f2bf(v.z); o.w = f2bf(v.w);
    reinterpret_cast<ushort4*>(dst)[i] = o;
  }
}

// ---------------------------------------------------------------- kernel 1: QKV GEMM (m97 structure)
// C[m,n] = dot(xb[m,:], W3b[n,:]) + b[n];  writes raw Q/K/V bf16 in [B,H,S,64] layout.
__global__ __launch_bounds__(256) void qkv_gemm_k(const ushort* __restrict__ xb,
                                                  const ushort* __restrict__ W3b,
                                                  const float* __restrict__ bqkv,
                                                  ushort* __restrict__ Qb,
                                                  ushort* __restrict__ Kb,
                                                  ushort* __restrict__ Vb) {
  __shared__ __align__(16) ushort As[128 * 64];  // linear (global_load_lds dest)
  __shared__ __align__(16) ushort Bs[128 * 64];
  const int t = threadIdx.x, wave = t >> 6, lane = t & 63;
  const int lr = lane & 15, kg = lane >> 4;
  const int wm = wave >> 1, wn = wave & 1;

  // XCD-bijective swizzle: nwg = 6144 = 8 * 768 -> each XCD gets 32 M-tiles x 24 N-tiles.
  const int flat = blockIdx.y * 24 + blockIdx.x;
  const int swz  = (flat & 7) * 768 + (flat >> 3);
  const int n0 = (swz % 24) * 128;
  const int m0 = (swz / 24) * 128;

  f32x4 acc[4][4];
#pragma unroll
  for (int i = 0; i < 4; i++)
#pragma unroll
    for (int j = 0; j < 4; j++) acc[i][j] = (f32x4){0.f, 0.f, 0.f, 0.f};

  const int srow = lane >> 3;           // row within 8-row chunk
  const int scol = (lane & 7) * 8;      // bf16 col within 64
  for (int kt = 0; kt < 1024; kt += 64) {
    __syncthreads();
#pragma unroll
    for (int i = 0; i < 4; i++) {
      const int c = wave * 4 + i;       // chunk: rows c*8..c*8+7
      gld_lds16(&xb [(size_t)(m0 + c * 8 + srow) * 1024 + kt + scol], As + c * 512);
      gld_lds16(&W3b[(size_t)(n0 + c * 8 + srow) * 1024 + kt + scol], Bs + c * 512);
    }
    __syncthreads();
#pragma unroll
    for (int ks = 0; ks < 64; ks += 32) {
      bf16x8 af[4], bfr[4];
#pragma unroll
      for (int i = 0; i < 4; i++)
        af[i] = *reinterpret_cast<const bf16x8*>(As + (wm * 64 + i * 16 + lr) * 64 + ks + kg * 8);
#pragma unroll
      for (int j = 0; j < 4; j++)
        bfr[j] = *reinterpret_cast<const bf16x8*>(Bs + (wn * 64 + j * 16 + lr) * 64 + ks + kg * 8);
#pragma unroll
      for (int i = 0; i < 4; i++)
#pragma unroll
        for (int j = 0; j < 4; j++)
          acc[i][j] = __builtin_amdgcn_mfma_f32_16x16x32_bf16(af[i], bfr[j], acc[i][j], 0, 0, 0);
    }
  }

  // epilogue: this wave's 64 cols = one full head of one part (128 | 1024 -> part uniform per wave)
  const int n0w  = n0 + wn * 64;
  const int part = n0w >> 10;          // 0=Q 1=K 2=V
  const int h    = (n0w & 1023) >> 6;  // head
  ushort* dst = (part == 0) ? Qb : (part == 1 ? Kb : Vb);
  const int bq     = m0 >> 13;
  const int s_base = (m0 & 8191) + wm * 64;
  const size_t hb  = ((size_t)(bq * Hc + h)) * Sc * 64;
#pragma unroll
  for (int j = 0; j < 4; j++) {
    int col = j * 16 + lr;
    float bias = bqkv[n0w + col];
#pragma unroll
    for (int i = 0; i < 4; i++) {
#pragma unroll
      for (int r = 0; r < 4; r++) {
        int s = s_base + i * 16 + kg * 4 + r;
        dst[hb + (size_t)s * 64 + col] = f2bf(acc[i][j][r] + bias);
      }
    }
  }
}

// ---------------------------------------------------------------- kernel 2: phi = sqrt(1+(Q W_p^T + b)^2), in place
__global__ __launch_bounds__(256) void phi_k(ushort* __restrict__ Qb, ushort* __restrict__ Kb,
                                             const ushort* __restrict__ Wpb,
                                             const float* __restrict__ bp) {
  __shared__ ushort Qs[256][72];
  __shared__ ushort Ws[64][72];
  const int t  = threadIdx.x;
  const int bh = blockIdx.y;
  const int s0 = blockIdx.x * 256;
  ushort* base = (blockIdx.z == 0 ? Qb : Kb) + (size_t)bh * Sc * 64 + (size_t)s0 * 64;

#pragma unroll
  for (int i = 0; i < 8; i++) {      // 2048 x ushort8 = 256 rows x 64
    int li = i * 256 + t;
    int r = li >> 3, c8 = li & 7;
    *reinterpret_cast<uint4*>(&Qs[r][c8 * 8]) = *reinterpret_cast<const uint4*>(&base[li * 8]);
  }
#pragma unroll
  for (int i = 0; i < 2; i++) {      // 512 x ushort8 = 64 x 64
    int li = i * 256 + t;
    int r = li >> 3, c8 = li & 7;
    *reinterpret_cast<uint4*>(&Ws[r][c8 * 8]) = *reinterpret_cast<const uint4*>(&Wpb[li * 8]);
  }
  __syncthreads();

  const int wave = t >> 6, lane = t & 63, lr = lane & 15, kg = lane >> 4;
  f32x4 acc[4][4];
#pragma unroll
  for (int i = 0; i < 4; i++)
#pragma unroll
    for (int j = 0; j < 4; j++) acc[i][j] = (f32x4){0.f, 0.f, 0.f, 0.f};

#pragma unroll
  for (int ks = 0; ks < 64; ks += 32) {
    bf16x8 af[4], bfr[4];
#pragma unroll
    for (int i = 0; i < 4; i++)
      af[i] = *reinterpret_cast<const bf16x8*>(&Qs[wave * 64 + i * 16 + lr][ks + kg * 8]);
#pragma unroll
    for (int j = 0; j < 4; j++)
      bfr[j] = *reinterpret_cast<const bf16x8*>(&Ws[j * 16 + lr][ks + kg * 8]);
#pragma unroll
    for (int i = 0; i < 4; i++)
#pragma unroll
      for (int j = 0; j < 4; j++)
        acc[i][j] = __builtin_amdgcn_mfma_f32_16x16x32_bf16(af[i], bfr[j], acc[i][j], 0, 0, 0);
  }

#pragma unroll
  for (int j = 0; j < 4; j++) {
    int col = j * 16 + lr;
    float bias = bp[col];
#pragma unroll
    for (int i = 0; i < 4; i++) {
#pragma unroll
      for (int r = 0; r < 4; r++) {
        int row = wave * 64 + i * 16 + kg * 4 + r;
        float p = acc[i][j][r] + bias;
        base[(size_t)row * 64 + col] = f2bf(sqrtf(1.f + p * p));
      }
    }
  }
}

// ---------------------------------------------------------------- kernel 3: per-chunk KTV partials + ksum partials
__global__ __launch_bounds__(256) void ktv_part_k(const ushort* __restrict__ Kphi,
                                                  const ushort* __restrict__ Vb,
                                                  float* __restrict__ KTVp,
                                                  float* __restrict__ ksump) {
  __shared__ ushort KsT[64][136];   // [a][s]  (transposed)
  __shared__ ushort VsT[64][136];   // [v][s]
  __shared__ float  red[64][65];
  const int t = threadIdx.x;
  const int chunk = blockIdx.x, bh = blockIdx.y;
  const int wave = t >> 6, lane = t & 63, lr = lane & 15, kg = lane >> 4;
  const size_t hb = (size_t)bh * Sc * 64;

  f32x4 acc[4][4];
#pragma unroll
  for (int i = 0; i < 4; i++)
#pragma unroll
    for (int j = 0; j < 4; j++) acc[i][j] = (f32x4){0.f, 0.f, 0.f, 0.f};
  float ks_acc = 0.f;

  for (int sub = 0; sub < 4; sub++) {
    const int sb = chunk * 512 + sub * 128;
    __syncthreads();
#pragma unroll
    for (int i = 0; i < 8; i++) {
      int li = i * 256 + t;              // ushort4 units
      int s = li >> 4, a4 = (li & 15) * 4;
      ushort4 kv = *reinterpret_cast<const ushort4*>(&Kphi[hb + (size_t)(sb + s) * 64 + a4]);
      ushort4 vv = *reinterpret_cast<const ushort4*>(&Vb[hb + (size_t)(sb + s) * 64 + a4]);
      KsT[a4 + 0][s] = kv.x; KsT[a4 + 1][s] = kv.y; KsT[a4 + 2][s] = kv.z; KsT[a4 + 3][s] = kv.w;
      VsT[a4 + 0][s] = vv.x; VsT[a4 + 1][s] = vv.y; VsT[a4 + 2][s] = vv.z; VsT[a4 + 3][s] = vv.w;
    }
    __syncthreads();
    {
      const int ko = wave * 32 + kg * 8;   // waves split the 128-deep K range
      bf16x8 af[4], bfr[4];
#pragma unroll
      for (int i = 0; i < 4; i++)
        af[i] = *reinterpret_cast<const bf16x8*>(&KsT[i * 16 + lr][ko]);
#pragma unroll
      for (int j = 0; j < 4; j++)
        bfr[j] = *reinterpret_cast<const bf16x8*>(&VsT[j * 16 + lr][ko]);
#pragma unroll
      for (int i = 0; i < 4; i++)
#pragma unroll
        for (int j = 0; j < 4; j++)
          acc[i][j] = __builtin_amdgcn_mfma_f32_16x16x32_bf16(af[i], bfr[j], acc[i][j], 0, 0, 0);
    }
    if (t < 64) {
      float s = 0.f;
      for (int ss = 0; ss < 128; ss++) s += bf2f(KsT[t][ss]);
      ks_acc += s;
    }
  }

  __syncthreads();
  for (int li = t; li < 64 * 65; li += 256) (&red[0][0])[li] = 0.f;
  __syncthreads();
  for (int w = 0; w < 4; w++) {
    if (wave == w) {
#pragma unroll
      for (int i = 0; i < 4; i++)
#pragma unroll
        for (int j = 0; j < 4; j++)
#pragma unroll
          for (int r = 0; r < 4; r++)
            red[i * 16 + kg * 4 + r][j * 16 + lr] += acc[i][j][r];
    }
    __syncthreads();
  }
  float* outp = KTVp + ((size_t)bh * 16 + chunk) * 4096;
  for (int li = t; li < 4096; li += 256) outp[li] = red[li >> 6][li & 63];
  if (t < 64) ksump[((size_t)bh * 16 + chunk) * 64 + t] = ks_acc;
}

// ---------------------------------------------------------------- kernel 3b: reduce partials
__global__ __launch_bounds__(256) void ktv_red_k(const float* __restrict__ KTVp,
                                                 const float* __restrict__ ksump,
                                                 float* __restrict__ KTV,
                                                 float* __restrict__ ksum) {
  const int bh = blockIdx.x, t = threadIdx.x;
  for (int li = t; li < 4096; li += 256) {
    float s = 0.f;
    for (int c = 0; c < 16; c++) s += KTVp[((size_t)bh * 16 + c) * 4096 + li];
    KTV[(size_t)bh * 4096 + li] = s;
  }
  if (t < 64) {
    float s = 0.f;
    for (int c = 0; c < 16; c++) s += ksump[((size_t)bh * 16 + c) * 64 + t];
    ksum[bh * 64 + t] = s;
  }
}

// ---------------------------------------------------------------- kernel 4: numerator + denominator + output
__global__ __launch_bounds__(256) void out_k(const ushort* __restrict__ Qphi,
                                             const float* __restrict__ KTV,
                                             const float* __restrict__ ksum,
                                             float* __restrict__ out) {
  __shared__ ushort Qs[256][72];
  __shared__ ushort BT[64][72];     // KTV^T in bf16: BT[v][a]
  __shared__ float  den[256];
  __shared__ float  kss[64];
  const int t = threadIdx.x;
  const int bh = blockIdx.y, s0 = blockIdx.x * 256;
  const ushort* qb = Qphi + (size_t)bh * Sc * 64 + (size_t)s0 * 64;

#pragma unroll
  for (int i = 0; i < 8; i++) {
    int li = i * 256 + t;
    int r = li >> 3, c8 = li & 7;
    *reinterpret_cast<uint4*>(&Qs[r][c8 * 8]) = *reinterpret_cast<const uint4*>(&qb[li * 8]);
  }
  for (int li = t; li < 4096; li += 256) {
    int a = li >> 6, v = li & 63;
    BT[v][a] = f2bf(KTV[(size_t)bh * 4096 + li]);
  }
  if (t < 64) kss[t] = ksum[bh * 64 + t];
  __syncthreads();

  {
    float d = 0.f;
    for (int a = 0; a < 64; a++) d += bf2f(Qs[t][a]) * kss[a];
    den[t] = d + EPSc;
  }
  __syncthreads();

  const int wave = t >> 6, lane = t & 63, lr = lane & 15, kg = lane >> 4;
  f32x4 acc[4][4];
#pragma unroll
  for (int i = 0; i < 4; i++)
#pragma unroll
    for (int j = 0; j < 4; j++) acc[i][j] = (f32x4){0.f, 0.f, 0.f, 0.f};

#pragma unroll
  for (int ks = 0; ks < 64; ks += 32) {
    bf16x8 af[4], bfr[4];
#pragma unroll
    for (int i = 0; i < 4; i++)
      af[i] = *reinterpret_cast<const bf16x8*>(&Qs[wave * 64 + i * 16 + lr][ks + kg * 8]);
#pragma unroll
    for (int j = 0; j < 4; j++)
      bfr[j] = *reinterpret_cast<const bf16x8*>(&BT[j * 16 + lr][ks + kg * 8]);
#pragma unroll
    for (int i = 0; i < 4; i++)
#pragma unroll
      for (int j = 0; j < 4; j++)
        acc[i][j] = __builtin_amdgcn_mfma_f32_16x16x32_bf16(af[i], bfr[j], acc[i][j], 0, 0, 0);
  }

  const int bq = bh >> 4, h = bh & 15;
#pragma unroll
  for (int i = 0; i < 4; i++) {
#pragma unroll
    for (int j = 0; j < 4; j++) {
#pragma unroll
      for (int r = 0; r < 4; r++) {
        int row = wave * 64 + i * 16 + kg * 4 + r;
        int s = s0 + row;
        int v = j * 16 + lr;
        out[((size_t)bq * Sc + s) * 1024 + h * 64 + v] = acc[i][j][r] / den[row];
      }
    }
  }
}

// ---------------------------------------------------------------- launch
extern "C" void kernel_launch(void* const* d_in, const int* in_sizes, int n_in,
                              void* d_out, int out_size, void* d_ws, size_t ws_size,
                              hipStream_t stream) {
  const float* x     = (const float*)d_in[0];
  const float* W_qkv = (const float*)d_in[1];
  const float* b_qkv = (const float*)d_in[2];
  const float* W_p   = (const float*)d_in[3];
  const float* b_p   = (const float*)d_in[4];
  float* out = (float*)d_out;

  size_t off = 0;
  auto carve = [&](size_t bytes) -> void* {
    void* p = (char*)d_ws + off;
    off += (bytes + 255) & ~(size_t)255;
    return p;
  };
  const size_t headElems = (size_t)BHc * Sc * 64;           // 33,554,432
  ushort* xb   = (ushort*)carve((size_t)Mc * Dc * 2);       // 64 MB bf16 x
  ushort* Qb   = (ushort*)carve(headElems * 2);
  ushort* Kb   = (ushort*)carve(headElems * 2);
  ushort* Vb   = (ushort*)carve(headElems * 2);
  ushort* W3b  = (ushort*)carve((size_t)N3c * Dc * 2);
  ushort* Wpb  = (ushort*)carve((size_t)ADc * HDc * 2);
  float*  KTVp = (float*)carve((size_t)BHc * 16 * 4096 * 4);
  float*  ksmp = (float*)carve((size_t)BHc * 16 * 64 * 4);
  float*  KTV  = (float*)carve((size_t)BHc * 4096 * 4);
  float*  ksum = (float*)carve((size_t)BHc * 64 * 4);
  (void)ws_size; (void)n_in; (void)in_sizes; (void)out_size;

  // 0: convert inputs to bf16
  cvt_bf16_k<<<(Mc * Dc / 4 + 255) / 256, 256, 0, stream>>>(x, xb, Mc * Dc / 4);
  cvt_bf16_k<<<(N3c * Dc / 4 + 255) / 256, 256, 0, stream>>>(W_qkv, W3b, N3c * Dc / 4);
  cvt_bf16_k<<<(ADc * HDc / 4 + 255) / 256, 256, 0, stream>>>(W_p, Wpb, ADc * HDc / 4);
  // 1: QKV GEMM -> raw Q/K/V (bias applied) in head layout
  qkv_gemm_k<<<dim3(N3c / 128, Mc / 128), 256, 0, stream>>>(xb, W3b, b_qkv, Qb, Kb, Vb);
  // 2: phi in place over Q and K
  phi_k<<<dim3(Sc / 256, BHc, 2), 256, 0, stream>>>(Qb, Kb, Wpb, b_p);
  // 3: KTV + ksum partials, then reduce
  ktv_part_k<<<dim3(16, BHc), 256, 0, stream>>>(Kb, Vb, KTVp, ksmp);
  ktv_red_k<<<BHc, 256, 0, stream>>>(KTVp, ksmp, KTV, ksum);
  // 4: output
  out_k<<<dim3(Sc / 256, BHc), 256, 0, stream>>>(Qb, KTV, ksum, out);
}

// Round 4
// 429.623 us; speedup vs baseline: 1.7102x; 1.2678x over previous
//
#include <hip/hip_runtime.h>
#include <hip/hip_bf16.h>
#include <cstdint>

// Problem constants
static constexpr int Bc  = 4;
static constexpr int Sc  = 8192;
static constexpr int Dc  = 1024;
static constexpr int Hc  = 16;
static constexpr int BHc = Bc * Hc;   // 64
static constexpr int Mc  = Bc * Sc;   // 32768
static constexpr int N3c = 3 * Dc;    // 3072
static constexpr float EPSc = 1e-6f;

using bf16x8 = __attribute__((ext_vector_type(8))) __bf16;
using f32x4  = __attribute__((ext_vector_type(4))) float;

__device__ __forceinline__ ushort f2bf(float f) {
  union { float f; uint32_t u; } v; v.f = f;
  uint32_t u = v.u;
  return (ushort)((u + 0x7fffu + ((u >> 16) & 1u)) >> 16);  // RNE
}
__device__ __forceinline__ float bf2f(ushort h) {
  union { uint32_t u; float f; } v; v.u = ((uint32_t)h) << 16;
  return v.f;
}

typedef const __attribute__((address_space(1))) unsigned int* gas_u32p;
typedef __attribute__((address_space(3))) unsigned int* las_u32p;
__device__ __forceinline__ void gld_lds16(const void* g, void* l) {
  __builtin_amdgcn_global_load_lds((gas_u32p)g, (las_u32p)l, 16, 0, 0);
}

// ---------------------------------------------------------------- kernel 0: fp32 -> bf16 convert (x)
__global__ __launch_bounds__(256) void cvt_bf16_k(const float* __restrict__ src,
                                                  ushort* __restrict__ dst, int n4) {
  int i = blockIdx.x * 256 + threadIdx.x;
  if (i < n4) {
    float4 v = reinterpret_cast<const float4*>(src)[i];
    ushort4 o; o.x = f2bf(v.x); o.y = f2bf(v.y); o.z = f2bf(v.z); o.w = f2bf(v.w);
    reinterpret_cast<ushort4*>(dst)[i] = o;
  }
}

// ---------------------------------------------------------------- kernel 1: weight fold
// Builds W3b[3072][1024] bf16 and bias3[3072] fp32:
//   rows 0..1023    : W_p @ W_Q  (per head),  bias = W_p b_Q + b_p
//   rows 1024..2047 : W_p @ W_K  (per head),  bias = W_p b_K + b_p
//   rows 2048..3071 : W_V (cvt),              bias = b_V
__global__ __launch_bounds__(256) void fold_k(const float* __restrict__ Wq,
                                              const float* __restrict__ Wp,
                                              const float* __restrict__ bq,
                                              const float* __restrict__ bp,
                                              ushort* __restrict__ W3b,
                                              float* __restrict__ bias3) {
  const int bx = blockIdx.x;          // 0..47
  const int p = bx >> 4, h = bx & 15;
  const int t = threadIdx.x;
  if (p == 2) {
    const int base = 2048 + h * 64;
    for (int li = t; li < 64 * 256; li += 256) {           // float4 units
      int r = li >> 8, c4 = (li & 255) * 4;
      float4 v = *reinterpret_cast<const float4*>(&Wq[(size_t)(base + r) * 1024 + c4]);
      ushort4 o; o.x = f2bf(v.x); o.y = f2bf(v.y); o.z = f2bf(v.z); o.w = f2bf(v.w);
      *reinterpret_cast<ushort4*>(&W3b[(size_t)(base + r) * 1024 + c4]) = o;
    }
    if (t < 64) bias3[base + t] = bq[base + t];
    return;
  }
  __shared__ ushort Ws[64 * 64];    // [a][hd]
  __shared__ ushort Tq[256 * 64];   // [d][hd]
  const int rbase = p * 1024 + h * 64;
  for (int li = t; li < 64 * 16; li += 256) {              // Wp: 4096 ele / 4
    int a = li >> 4, h4 = (li & 15) * 4;
    float4 v = *reinterpret_cast<const float4*>(&Wp[a * 64 + h4]);
    ushort4 o; o.x = f2bf(v.x); o.y = f2bf(v.y); o.z = f2bf(v.z); o.w = f2bf(v.w);
    *reinterpret_cast<ushort4*>(&Ws[a * 64 + h4]) = o;
  }
  if (t < 64) {
    float s = bp[t];
    for (int hd = 0; hd < 64; ++hd) s += Wp[t * 64 + hd] * bq[rbase + hd];
    bias3[rbase + t] = s;
  }
  const int w = t >> 6, lane = t & 63, lr = lane & 15, kg = lane >> 4;
  for (int dt = 0; dt < 4; ++dt) {
    __syncthreads();
    for (int li = t; li < 64 * 64; li += 256) {            // 64 hd x 64 d4-chunks
      int hd = li >> 6, d4 = (li & 63) * 4;
      float4 v = *reinterpret_cast<const float4*>(&Wq[(size_t)(rbase + hd) * 1024 + dt * 256 + d4]);
      Tq[(d4 + 0) * 64 + hd] = f2bf(v.x);
      Tq[(d4 + 1) * 64 + hd] = f2bf(v.y);
      Tq[(d4 + 2) * 64 + hd] = f2bf(v.z);
      Tq[(d4 + 3) * 64 + hd] = f2bf(v.w);
    }
    __syncthreads();
    f32x4 acc[4][4];
#pragma unroll
    for (int i = 0; i < 4; i++)
#pragma unroll
      for (int j = 0; j < 4; j++) acc[i][j] = (f32x4){0.f, 0.f, 0.f, 0.f};
#pragma unroll
    for (int kk = 0; kk < 2; ++kk) {
      bf16x8 af[4], bfr[4];
#pragma unroll
      for (int i = 0; i < 4; i++)
        af[i] = *reinterpret_cast<const bf16x8*>(&Ws[(i * 16 + lr) * 64 + kk * 32 + kg * 8]);
#pragma unroll
      for (int j = 0; j < 4; j++)
        bfr[j] = *reinterpret_cast<const bf16x8*>(&Tq[(w * 64 + j * 16 + lr) * 64 + kk * 32 + kg * 8]);
#pragma unroll
      for (int i = 0; i < 4; i++)
#pragma unroll
        for (int j = 0; j < 4; j++)
          acc[i][j] = __builtin_amdgcn_mfma_f32_16x16x32_bf16(af[i], bfr[j], acc[i][j], 0, 0, 0);
    }
#pragma unroll
    for (int i = 0; i < 4; i++)
#pragma unroll
      for (int j = 0; j < 4; j++)
#pragma unroll
        for (int r = 0; r < 4; r++)
          W3b[(size_t)(rbase + i * 16 + kg * 4 + r) * 1024 + dt * 256 + w * 64 + j * 16 + lr] =
              f2bf(acc[i][j][r]);
  }
}

// ---------------------------------------------------------------- kernel 2: pipelined QKV GEMM + fused phi
// 256x256 tile, BK=32, 8 waves, 3-buffer LDS ring, counted vmcnt(4), raw barriers,
// both-sides XOR chunk swizzle. Outputs:
//   phiQ -> [B,H,S,64] bf16 (normal),  phiK -> [B,H,64,S] bf16 (T),  V -> [B,H,64,S] bf16 (T)
__global__ __launch_bounds__(512, 2) void gemm_pipe_k(const ushort* __restrict__ xb,
                                                      const ushort* __restrict__ W3b,
                                                      const float* __restrict__ bias3,
                                                      ushort* __restrict__ Qb,
                                                      ushort* __restrict__ KTb,
                                                      ushort* __restrict__ VTb) {
  __shared__ __align__(16) ushort As[3 * 8192];   // 3 bufs x [256][32]
  __shared__ __align__(16) ushort Bs[3 * 8192];
  const int t = threadIdx.x, wave = t >> 6, lane = t & 63;
  const int lr = lane & 15, kg = lane >> 4;
  const int wr = wave >> 2, wc = wave & 3;

  // XCD-bijective swizzle: 1536 = 8 * 192; each XCD: 16 m-tiles x 12 n-tiles, n fastest.
  const int flat = blockIdx.x;
  const int swz  = (flat & 7) * 192 + (flat >> 3);
  const int n0 = (swz % 12) * 256;
  const int m0 = (swz / 12) * 256;

  // staging thread params (both A and B): issue is in {0,1}:
  //   lds elem = buf*8192 + is*4096 + t*8 ; row = is*128 + (t>>2); c' = t&3
  //   global chunk c = c' ^ (row&3) ^ ((row>>2)&3) = (t&3) ^ ((t>>2)&3) ^ ((t>>4)&3)
  const int srow = t >> 2;                                   // 0..127
  const int sc   = (t & 3) ^ ((t >> 2) & 3) ^ ((t >> 4) & 3);
  const int wb   = (t >> 6) * 512;                           // wave-uniform lds base (elems)

  auto STAGE = [&](int tile, int buf) {
    const int kt = tile * 32;
#pragma unroll
    for (int is = 0; is < 2; ++is) {
      gld_lds16(xb  + (size_t)(m0 + is * 128 + srow) * 1024 + kt + sc * 8,
                As + buf * 8192 + is * 4096 + wb);
      gld_lds16(W3b + (size_t)(n0 + is * 128 + srow) * 1024 + kt + sc * 8,
                Bs + buf * 8192 + is * 4096 + wb);
    }
  };

  f32x4 acc[8][4];
#pragma unroll
  for (int f = 0; f < 8; f++)
#pragma unroll
    for (int j = 0; j < 4; j++) acc[f][j] = (f32x4){0.f, 0.f, 0.f, 0.f};

  // read-side swizzled fragment bases (row&3 == lr&3, (row>>2)&3 == (lr>>2)&3)
  const int swr = (lr & 3) ^ ((lr >> 2) & 3);
  const int cA  = (kg ^ swr) * 8;
  const ushort* Ard = As + (wr * 128 + lr) * 32 + cA;   // + f*512 + buf*8192
  const ushort* Brd = Bs + (wc * 64 + lr) * 32 + cA;    // + j*512 + buf*8192

  auto COMPUTE = [&](int buf) {
    bf16x8 af[8], bfr[4];
    const ushort* Ab = Ard + buf * 8192;
    const ushort* Bb = Brd + buf * 8192;
#pragma unroll
    for (int f = 0; f < 8; f++) af[f] = *reinterpret_cast<const bf16x8*>(Ab + f * 512);
#pragma unroll
    for (int j = 0; j < 4; j++) bfr[j] = *reinterpret_cast<const bf16x8*>(Bb + j * 512);
    __builtin_amdgcn_s_setprio(1);
#pragma unroll
    for (int f = 0; f < 8; f++)
#pragma unroll
      for (int j = 0; j < 4; j++)
        acc[f][j] = __builtin_amdgcn_mfma_f32_16x16x32_bf16(af[f], bfr[j], acc[f][j], 0, 0, 0);
    __builtin_amdgcn_s_setprio(0);
  };

  // prologue
  STAGE(0, 0);
  STAGE(1, 1);
  asm volatile("s_waitcnt vmcnt(4)" ::: "memory");
  __builtin_amdgcn_s_barrier();

  int bt = 0, bn = 1, b2 = 2;
#pragma unroll 3
  for (int tile = 0; tile < 30; ++tile) {
    STAGE(tile + 2, b2);
    COMPUTE(bt);
    asm volatile("s_waitcnt vmcnt(4)" ::: "memory");
    __builtin_amdgcn_s_barrier();
    int tmp = bt; bt = bn; bn = b2; b2 = tmp;
  }
  COMPUTE(0);                                   // tile 30 (buf 0)
  asm volatile("s_waitcnt vmcnt(0)" ::: "memory");
  __builtin_amdgcn_s_barrier();
  COMPUTE(1);                                   // tile 31 (buf 1)

  // epilogue: wave's 64 cols = one head of one part (n0 multiple of 256)
  const int n0w  = n0 + wc * 64;
  const int part = n0w >> 10;           // 0=phiQ 1=phiK(T) 2=V(T)
  const int h    = (n0w & 1023) >> 6;
  const int bq   = m0 >> 13;
  const int s_base = (m0 & 8191) + wr * 128;
  float bias[4];
#pragma unroll
  for (int j = 0; j < 4; j++) bias[j] = bias3[n0w + j * 16 + lr];

  if (part == 0) {
    ushort* dst = Qb + ((size_t)(bq * Hc + h)) * Sc * 64;
#pragma unroll
    for (int f = 0; f < 8; f++)
#pragma unroll
      for (int j = 0; j < 4; j++)
#pragma unroll
        for (int r = 0; r < 4; r++) {
          float p = acc[f][j][r] + bias[j];
          dst[(size_t)(s_base + f * 16 + kg * 4 + r) * 64 + j * 16 + lr] =
              f2bf(sqrtf(1.f + p * p));
        }
  } else {
    ushort* dst = ((part == 1) ? KTb : VTb) + ((size_t)(bq * Hc + h)) * 64 * Sc;
#pragma unroll
    for (int f = 0; f < 8; f++) {
      const int s = s_base + f * 16 + kg * 4;
#pragma unroll
      for (int j = 0; j < 4; j++) {
        ushort4 o;
        if (part == 1) {
#pragma unroll
          for (int r = 0; r < 4; r++) {
            float p = acc[f][j][r] + bias[j];
            (&o.x)[r] = f2bf(sqrtf(1.f + p * p));
          }
        } else {
#pragma unroll
          for (int r = 0; r < 4; r++) (&o.x)[r] = f2bf(acc[f][j][r] + bias[j]);
        }
        *reinterpret_cast<ushort4*>(&dst[(size_t)(j * 16 + lr) * Sc + s]) = o;
      }
    }
  }
}

// ---------------------------------------------------------------- kernel 3: KTV + ksum partials (T-layout inputs)
// KTV[a][v] = sum_s phiKT[a][s] * VT[v][s];  block = (1024-s chunk, bh)
__global__ __launch_bounds__(256) void ktv_part_k(const ushort* __restrict__ KT,
                                                  const ushort* __restrict__ VT,
                                                  float* __restrict__ KTVp,
                                                  float* __restrict__ ksump) {
  __shared__ __align__(16) ushort Ks[64 * 128];
  __shared__ __align__(16) ushort Vs[64 * 128];
  __shared__ float red[64][65];
  const int t = threadIdx.x, chunk = blockIdx.x, bh = blockIdx.y;
  const int wave = t >> 6, lane = t & 63, lr = lane & 15, kg = lane >> 4;
  const size_t hb = (size_t)bh * 64 * Sc;
  const int s0 = chunk * 1024;

  f32x4 acc[4][4];
#pragma unroll
  for (int i = 0; i < 4; i++)
#pragma unroll
    for (int j = 0; j < 4; j++) acc[i][j] = (f32x4){0.f, 0.f, 0.f, 0.f};
  float ks_acc = 0.f;

  // staging: issue is in {0..3}: lds elem = is*2048 + t*8; row = is*16 + (t>>4); c' = t&15
  const int srl = t >> 4;                       // row low
  const int scc = (t & 15) ^ ((t >> 4) & 7);    // global chunk (row&7 == (t>>4)&7)
  const int wb  = (t >> 6) * 512;
  // read-side: c_read = wave*4 + kg; c' = c_read ^ (lr&7)
  const int cR = ((wave * 4 + kg) ^ (lr & 7)) * 8;

  for (int st = 0; st < 8; ++st) {
    const int sb = s0 + st * 128;
    __syncthreads();
#pragma unroll
    for (int is = 0; is < 4; ++is) {
      const int row = is * 16 + srl;
      gld_lds16(KT + hb + (size_t)row * Sc + sb + scc * 8, Ks + is * 2048 + wb);
      gld_lds16(VT + hb + (size_t)row * Sc + sb + scc * 8, Vs + is * 2048 + wb);
    }
    __syncthreads();
    {
      bf16x8 af[4], bfr[4];
#pragma unroll
      for (int i = 0; i < 4; i++)
        af[i] = *reinterpret_cast<const bf16x8*>(&Ks[(i * 16 + lr) * 128 + cR]);
#pragma unroll
      for (int j = 0; j < 4; j++)
        bfr[j] = *reinterpret_cast<const bf16x8*>(&Vs[(j * 16 + lr) * 128 + cR]);
#pragma unroll
      for (int i = 0; i < 4; i++)
#pragma unroll
        for (int j = 0; j < 4; j++)
          acc[i][j] = __builtin_amdgcn_mfma_f32_16x16x32_bf16(af[i], bfr[j], acc[i][j], 0, 0, 0);
    }
    if (t < 64) {  // row t is a-index; swizzle is a within-row permutation -> plain sum ok
      float s = 0.f;
      for (int e = 0; e < 128; e++) s += bf2f(Ks[t * 128 + e]);
      ks_acc += s;
    }
  }

  __syncthreads();
  for (int li = t; li < 64 * 65; li += 256) (&red[0][0])[li] = 0.f;
  __syncthreads();
  for (int w = 0; w < 4; w++) {
    if (wave == w) {
#pragma unroll
      for (int i = 0; i < 4; i++)
#pragma unroll
        for (int j = 0; j < 4; j++)
#pragma unroll
          for (int r = 0; r < 4; r++)
            red[i * 16 + kg * 4 + r][j * 16 + lr] += acc[i][j][r];
    }
    __syncthreads();
  }
  float* outp = KTVp + ((size_t)bh * 8 + chunk) * 4096;
  for (int li = t; li < 4096; li += 256) outp[li] = red[li >> 6][li & 63];
  if (t < 64) ksump[((size_t)bh * 8 + chunk) * 64 + t] = ks_acc;
}

// ---------------------------------------------------------------- kernel 3b: reduce partials
__global__ __launch_bounds__(256) void ktv_red_k(const float* __restrict__ KTVp,
                                                 const float* __restrict__ ksump,
                                                 float* __restrict__ KTV,
                                                 float* __restrict__ ksum) {
  const int bh = blockIdx.x, t = threadIdx.x;
  for (int li = t; li < 4096; li += 256) {
    float s = 0.f;
    for (int c = 0; c < 8; c++) s += KTVp[((size_t)bh * 8 + c) * 4096 + li];
    KTV[(size_t)bh * 4096 + li] = s;
  }
  if (t < 64) {
    float s = 0.f;
    for (int c = 0; c < 8; c++) s += ksump[((size_t)bh * 8 + c) * 64 + t];
    ksum[bh * 64 + t] = s;
  }
}

// ---------------------------------------------------------------- kernel 4: numerator + denominator + output
__global__ __launch_bounds__(256) void out_k(const ushort* __restrict__ Qphi,
                                             const float* __restrict__ KTV,
                                             const float* __restrict__ ksum,
                                             float* __restrict__ out) {
  __shared__ ushort Qs[256][72];
  __shared__ ushort BT[64][72];     // KTV^T in bf16: BT[v][a]
  __shared__ float  den[256];
  __shared__ float  kss[64];
  const int t = threadIdx.x;
  const int bh = blockIdx.y, s0 = blockIdx.x * 256;
  const ushort* qb = Qphi + (size_t)bh * Sc * 64 + (size_t)s0 * 64;

#pragma unroll
  for (int i = 0; i < 8; i++) {
    int li = i * 256 + t;
    int r = li >> 3, c8 = li & 7;
    *reinterpret_cast<uint4*>(&Qs[r][c8 * 8]) = *reinterpret_cast<const uint4*>(&qb[li * 8]);
  }
  for (int li = t; li < 4096; li += 256) {
    int a = li >> 6, v = li & 63;
    BT[v][a] = f2bf(KTV[(size_t)bh * 4096 + li]);
  }
  if (t < 64) kss[t] = ksum[bh * 64 + t];
  __syncthreads();

  {
    float d = 0.f;
    for (int a = 0; a < 64; a++) d += bf2f(Qs[t][a]) * kss[a];
    den[t] = d + EPSc;
  }
  __syncthreads();

  const int wave = t >> 6, lane = t & 63, lr = lane & 15, kg = lane >> 4;
  f32x4 acc[4][4];
#pragma unroll
  for (int i = 0; i < 4; i++)
#pragma unroll
    for (int j = 0; j < 4; j++) acc[i][j] = (f32x4){0.f, 0.f, 0.f, 0.f};

#pragma unroll
  for (int ks = 0; ks < 64; ks += 32) {
    bf16x8 af[4], bfr[4];
#pragma unroll
    for (int i = 0; i < 4; i++)
      af[i] = *reinterpret_cast<const bf16x8*>(&Qs[wave * 64 + i * 16 + lr][ks + kg * 8]);
#pragma unroll
    for (int j = 0; j < 4; j++)
      bfr[j] = *reinterpret_cast<const bf16x8*>(&BT[j * 16 + lr][ks + kg * 8]);
#pragma unroll
    for (int i = 0; i < 4; i++)
#pragma unroll
      for (int j = 0; j < 4; j++)
        acc[i][j] = __builtin_amdgcn_mfma_f32_16x16x32_bf16(af[i], bfr[j], acc[i][j], 0, 0, 0);
  }

  const int bq = bh >> 4, h = bh & 15;
#pragma unroll
  for (int i = 0; i < 4; i++) {
#pragma unroll
    for (int j = 0; j < 4; j++) {
#pragma unroll
      for (int r = 0; r < 4; r++) {
        int row = wave * 64 + i * 16 + kg * 4 + r;
        int s = s0 + row;
        int v = j * 16 + lr;
        out[((size_t)bq * Sc + s) * 1024 + h * 64 + v] = acc[i][j][r] / den[row];
      }
    }
  }
}

// ---------------------------------------------------------------- launch
extern "C" void kernel_launch(void* const* d_in, const int* in_sizes, int n_in,
                              void* d_out, int out_size, void* d_ws, size_t ws_size,
                              hipStream_t stream) {
  const float* x     = (const float*)d_in[0];
  const float* W_qkv = (const float*)d_in[1];
  const float* b_qkv = (const float*)d_in[2];
  const float* W_p   = (const float*)d_in[3];
  const float* b_p   = (const float*)d_in[4];
  float* out = (float*)d_out;

  size_t off = 0;
  auto carve = [&](size_t bytes) -> void* {
    void* p = (char*)d_ws + off;
    off += (bytes + 255) & ~(size_t)255;
    return p;
  };
  const size_t headElems = (size_t)BHc * Sc * 64;           // 33,554,432
  ushort* xb    = (ushort*)carve((size_t)Mc * Dc * 2);      // 64 MB
  ushort* Qb    = (ushort*)carve(headElems * 2);            // phiQ  [B,H,S,64]
  ushort* KTb   = (ushort*)carve(headElems * 2);            // phiK  [B,H,64,S]
  ushort* VTb   = (ushort*)carve(headElems * 2);            // V     [B,H,64,S]
  ushort* W3b   = (ushort*)carve((size_t)N3c * Dc * 2);
  float*  bias3 = (float*)carve((size_t)N3c * 4);
  float*  KTVp  = (float*)carve((size_t)BHc * 8 * 4096 * 4);
  float*  ksmp  = (float*)carve((size_t)BHc * 8 * 64 * 4);
  float*  KTV   = (float*)carve((size_t)BHc * 4096 * 4);
  float*  ksum  = (float*)carve((size_t)BHc * 64 * 4);
  (void)ws_size; (void)n_in; (void)in_sizes; (void)out_size;

  cvt_bf16_k<<<Mc * Dc / 4 / 256, 256, 0, stream>>>(x, xb, Mc * Dc / 4);
  fold_k<<<48, 256, 0, stream>>>(W_qkv, W_p, b_qkv, b_p, W3b, bias3);
  gemm_pipe_k<<<(Mc / 256) * (N3c / 256), 512, 0, stream>>>(xb, W3b, bias3, Qb, KTb, VTb);
  ktv_part_k<<<dim3(8, BHc), 256, 0, stream>>>(KTb, VTb, KTVp, ksmp);
  ktv_red_k<<<BHc, 256, 0, stream>>>(KTVp, ksmp, KTV, ksum);
  out_k<<<dim3(Sc / 256, BHc), 256, 0, stream>>>(Qb, KTV, ksum, out);
}

// Round 5
// 417.497 us; speedup vs baseline: 1.7599x; 1.0290x over previous
//
#include <hip/hip_runtime.h>
#include <hip/hip_bf16.h>
#include <cstdint>

// Problem constants
static constexpr int Bc  = 4;
static constexpr int Sc  = 8192;
static constexpr int Dc  = 1024;
static constexpr int Hc  = 16;
static constexpr int BHc = Bc * Hc;   // 64
static constexpr int Mc  = Bc * Sc;   // 32768
static constexpr int N3c = 3 * Dc;    // 3072
static constexpr float EPSc = 1e-6f;

using bf16x8 = __attribute__((ext_vector_type(8))) __bf16;
using f32x4  = __attribute__((ext_vector_type(4))) float;

__device__ __forceinline__ ushort f2bf(float f) {
  union { float f; uint32_t u; } v; v.f = f;
  uint32_t u = v.u;
  return (ushort)((u + 0x7fffu + ((u >> 16) & 1u)) >> 16);  // RNE
}
__device__ __forceinline__ float bf2f(ushort h) {
  union { uint32_t u; float f; } v; v.u = ((uint32_t)h) << 16;
  return v.f;
}

typedef const __attribute__((address_space(1))) unsigned int* gas_u32p;
typedef __attribute__((address_space(3))) unsigned int* las_u32p;
__device__ __forceinline__ void gld_lds16(const void* g, void* l) {
  __builtin_amdgcn_global_load_lds((gas_u32p)g, (las_u32p)l, 16, 0, 0);
}

// ---------------------------------------------------------------- kernel 0: fp32 -> bf16 convert (x)
__global__ __launch_bounds__(256) void cvt_bf16_k(const float* __restrict__ src,
                                                  ushort* __restrict__ dst, int n4) {
  for (int i = blockIdx.x * 256 + threadIdx.x; i < n4; i += gridDim.x * 256) {
    float4 v = reinterpret_cast<const float4*>(src)[i];
    ushort4 o; o.x = f2bf(v.x); o.y = f2bf(v.y); o.z = f2bf(v.z); o.w = f2bf(v.w);
    reinterpret_cast<ushort4*>(dst)[i] = o;
  }
}

// ---------------------------------------------------------------- kernel 1: weight fold
// Builds W3b[3072][1024] bf16 and bias3[3072] fp32:
//   rows 0..1023    : W_p @ W_Q  (per head),  bias = W_p b_Q + b_p
//   rows 1024..2047 : W_p @ W_K  (per head),  bias = W_p b_K + b_p
//   rows 2048..3071 : W_V (cvt),              bias = b_V
__global__ __launch_bounds__(256) void fold_k(const float* __restrict__ Wq,
                                              const float* __restrict__ Wp,
                                              const float* __restrict__ bq,
                                              const float* __restrict__ bp,
                                              ushort* __restrict__ W3b,
                                              float* __restrict__ bias3) {
  const int bx = blockIdx.x;          // 0..47
  const int p = bx >> 4, h = bx & 15;
  const int t = threadIdx.x;
  if (p == 2) {
    const int base = 2048 + h * 64;
    for (int li = t; li < 64 * 256; li += 256) {           // float4 units
      int r = li >> 8, c4 = (li & 255) * 4;
      float4 v = *reinterpret_cast<const float4*>(&Wq[(size_t)(base + r) * 1024 + c4]);
      ushort4 o; o.x = f2bf(v.x); o.y = f2bf(v.y); o.z = f2bf(v.z); o.w = f2bf(v.w);
      *reinterpret_cast<ushort4*>(&W3b[(size_t)(base + r) * 1024 + c4]) = o;
    }
    if (t < 64) bias3[base + t] = bq[base + t];
    return;
  }
  __shared__ ushort Ws[64 * 64];    // [a][hd]
  __shared__ ushort Tq[256 * 64];   // [d][hd]
  const int rbase = p * 1024 + h * 64;
  for (int li = t; li < 64 * 16; li += 256) {              // Wp: 4096 ele / 4
    int a = li >> 4, h4 = (li & 15) * 4;
    float4 v = *reinterpret_cast<const float4*>(&Wp[a * 64 + h4]);
    ushort4 o; o.x = f2bf(v.x); o.y = f2bf(v.y); o.z = f2bf(v.z); o.w = f2bf(v.w);
    *reinterpret_cast<ushort4*>(&Ws[a * 64 + h4]) = o;
  }
  if (t < 64) {
    float s = bp[t];
    for (int hd = 0; hd < 64; ++hd) s += Wp[t * 64 + hd] * bq[rbase + hd];
    bias3[rbase + t] = s;
  }
  const int w = t >> 6, lane = t & 63, lr = lane & 15, kg = lane >> 4;
  for (int dt = 0; dt < 4; ++dt) {
    __syncthreads();
    for (int li = t; li < 64 * 64; li += 256) {            // 64 hd x 64 d4-chunks
      int hd = li >> 6, d4 = (li & 63) * 4;
      float4 v = *reinterpret_cast<const float4*>(&Wq[(size_t)(rbase + hd) * 1024 + dt * 256 + d4]);
      Tq[(d4 + 0) * 64 + hd] = f2bf(v.x);
      Tq[(d4 + 1) * 64 + hd] = f2bf(v.y);
      Tq[(d4 + 2) * 64 + hd] = f2bf(v.z);
      Tq[(d4 + 3) * 64 + hd] = f2bf(v.w);
    }
    __syncthreads();
    f32x4 acc[4][4];
#pragma unroll
    for (int i = 0; i < 4; i++)
#pragma unroll
      for (int j = 0; j < 4; j++) acc[i][j] = (f32x4){0.f, 0.f, 0.f, 0.f};
#pragma unroll
    for (int kk = 0; kk < 2; ++kk) {
      bf16x8 af[4], bfr[4];
#pragma unroll
      for (int i = 0; i < 4; i++)
        af[i] = *reinterpret_cast<const bf16x8*>(&Ws[(i * 16 + lr) * 64 + kk * 32 + kg * 8]);
#pragma unroll
      for (int j = 0; j < 4; j++)
        bfr[j] = *reinterpret_cast<const bf16x8*>(&Tq[(w * 64 + j * 16 + lr) * 64 + kk * 32 + kg * 8]);
#pragma unroll
      for (int i = 0; i < 4; i++)
#pragma unroll
        for (int j = 0; j < 4; j++)
          acc[i][j] = __builtin_amdgcn_mfma_f32_16x16x32_bf16(af[i], bfr[j], acc[i][j], 0, 0, 0);
    }
#pragma unroll
    for (int i = 0; i < 4; i++)
#pragma unroll
      for (int j = 0; j < 4; j++)
#pragma unroll
        for (int r = 0; r < 4; r++)
          W3b[(size_t)(rbase + i * 16 + kg * 4 + r) * 1024 + dt * 256 + w * 64 + j * 16 + lr] =
              f2bf(acc[i][j][r]);
  }
}

// ---------------------------------------------------------------- kernel 2: pipelined QKV GEMM + fused phi
// 256x256 tile, BK=32, 8 waves, 4-buffer LDS ring (depth-3 prefetch), counted vmcnt(8),
// raw barriers, exact conflict-free both-sides XOR chunk swizzle. Outputs:
//   phiQ -> [B,H,S,64] bf16,  phiK -> [B,H,64,S] bf16 (T),  V -> [B,H,64,S] bf16 (T)
__global__ __launch_bounds__(512, 2) void gemm_pipe_k(const ushort* __restrict__ xb,
                                                      const ushort* __restrict__ W3b,
                                                      const float* __restrict__ bias3,
                                                      ushort* __restrict__ Qb,
                                                      ushort* __restrict__ KTb,
                                                      ushort* __restrict__ VTb) {
  __shared__ __align__(16) ushort As[4 * 8192];   // 4 bufs x [256 rows][32 k] = 64 KB
  __shared__ __align__(16) ushort Bs[4 * 8192];   // 64 KB
  const int t = threadIdx.x, wave = t >> 6, lane = t & 63;
  const int lr = lane & 15, kg = lane >> 4;
  const int wr = wave >> 2, wc = wave & 3;

  // XCD-bijective swizzle: 1536 = 8 * 192; each XCD: 16 m-tiles x 12 n-tiles, n fastest.
  const int flat = blockIdx.x;
  const int swz  = (flat & 7) * 192 + (flat >> 3);
  const int n0 = (swz % 12) * 256;
  const int m0 = (swz / 12) * 256;

  // Staging: load li = is*512 + t (8 bf16 each). lds elem = li*8; row = li>>2 (in half is),
  // lds chunk pos p = li&3. Conflict-free involution: global chunk g = p ^ ((row>>1)&3)
  //   = (t&3) ^ ((t>>3)&3)   (is*128 rows and wave offsets vanish mod 4).
  const int srow = t >> 2;                          // row within 128-row half
  const int sg   = (t & 3) ^ ((t >> 3) & 3);        // global 8-elem chunk
  const int swb  = wave * 512;                      // wave-uniform lds elem base

  auto STAGE = [&](int tile, int buf) {
    const int kt = tile * 32;
#pragma unroll
    for (int is = 0; is < 2; ++is) {
      gld_lds16(xb  + (size_t)(m0 + is * 128 + srow) * 1024 + kt + sg * 8,
                As + buf * 8192 + is * 4096 + swb);
      gld_lds16(W3b + (size_t)(n0 + is * 128 + srow) * 1024 + kt + sg * 8,
                Bs + buf * 8192 + is * 4096 + swb);
    }
  };

  f32x4 acc[8][4];
#pragma unroll
  for (int f = 0; f < 8; f++)
#pragma unroll
    for (int j = 0; j < 4; j++) acc[f][j] = (f32x4){0.f, 0.f, 0.f, 0.f};

  // Read side: row = (wr*128|wc*64) + frag*16 + lr ; (row>>1)&3 == (lr>>1)&3 for all frags.
  // chunk pos = kg ^ ((lr>>1)&3)  -> per-instruction exactly 8 bank-slots/bank (min issue).
  const int cp = (kg ^ ((lr >> 1) & 3)) * 8;
  const ushort* Ard = As + (wr * 128 + lr) * 32 + cp;   // + f*512 + buf*8192
  const ushort* Brd = Bs + (wc * 64 + lr) * 32 + cp;    // + j*512 + buf*8192

  auto COMPUTE = [&](int buf) {
    bf16x8 af[8], bfr[4];
    const ushort* Ab = Ard + buf * 8192;
    const ushort* Bb = Brd + buf * 8192;
#pragma unroll
    for (int f = 0; f < 8; f++) af[f] = *reinterpret_cast<const bf16x8*>(Ab + f * 512);
#pragma unroll
    for (int j = 0; j < 4; j++) bfr[j] = *reinterpret_cast<const bf16x8*>(Bb + j * 512);
    __builtin_amdgcn_s_setprio(1);
#pragma unroll
    for (int f = 0; f < 8; f++)
#pragma unroll
      for (int j = 0; j < 4; j++)
        acc[f][j] = __builtin_amdgcn_mfma_f32_16x16x32_bf16(af[f], bfr[j], acc[f][j], 0, 0, 0);
    __builtin_amdgcn_s_setprio(0);
  };

  // prologue: stage tiles 0..2 (12 loads), wait tile 0 (8 remain outstanding)
  STAGE(0, 0);
  STAGE(1, 1);
  STAGE(2, 2);
  asm volatile("s_waitcnt vmcnt(8)" ::: "memory");
  __builtin_amdgcn_s_barrier();

  // steady state: tiles 0..27 (buf = tile&3 compile-time via 4x unroll)
#pragma unroll 1
  for (int i = 0; i < 7; ++i) {
    const int tb = i * 4;
#pragma unroll
    for (int j = 0; j < 4; ++j) {
      STAGE(tb + j + 3, (j + 3) & 3);
      COMPUTE(j);
      asm volatile("s_waitcnt vmcnt(8)" ::: "memory");
      __builtin_amdgcn_s_barrier();
    }
  }
  // t=28: stage last tile (31)
  STAGE(31, 3);
  COMPUTE(0);
  asm volatile("s_waitcnt vmcnt(8)" ::: "memory");
  __builtin_amdgcn_s_barrier();
  // t=29
  COMPUTE(1);
  asm volatile("s_waitcnt vmcnt(4)" ::: "memory");
  __builtin_amdgcn_s_barrier();
  // t=30
  COMPUTE(2);
  asm volatile("s_waitcnt vmcnt(0)" ::: "memory");
  __builtin_amdgcn_s_barrier();
  // t=31
  COMPUTE(3);

  // epilogue: wave's 64 cols = one head of one part (n0 multiple of 256)
  const int n0w  = n0 + wc * 64;
  const int part = n0w >> 10;           // 0=phiQ 1=phiK(T) 2=V(T)
  const int h    = (n0w & 1023) >> 6;
  const int bq   = m0 >> 13;
  const int s_base = (m0 & 8191) + wr * 128;
  float bias[4];
#pragma unroll
  for (int j = 0; j < 4; j++) bias[j] = bias3[n0w + j * 16 + lr];

  if (part == 0) {
    ushort* dst = Qb + ((size_t)(bq * Hc + h)) * Sc * 64;
#pragma unroll
    for (int f = 0; f < 8; f++)
#pragma unroll
      for (int j = 0; j < 4; j++)
#pragma unroll
        for (int r = 0; r < 4; r++) {
          float p = acc[f][j][r] + bias[j];
          dst[(size_t)(s_base + f * 16 + kg * 4 + r) * 64 + j * 16 + lr] =
              f2bf(sqrtf(1.f + p * p));
        }
  } else {
    ushort* dst = ((part == 1) ? KTb : VTb) + ((size_t)(bq * Hc + h)) * 64 * Sc;
#pragma unroll
    for (int f = 0; f < 8; f++) {
      const int s = s_base + f * 16 + kg * 4;
#pragma unroll
      for (int j = 0; j < 4; j++) {
        ushort4 o;
        if (part == 1) {
#pragma unroll
          for (int r = 0; r < 4; r++) {
            float p = acc[f][j][r] + bias[j];
            (&o.x)[r] = f2bf(sqrtf(1.f + p * p));
          }
        } else {
#pragma unroll
          for (int r = 0; r < 4; r++) (&o.x)[r] = f2bf(acc[f][j][r] + bias[j]);
        }
        *reinterpret_cast<ushort4*>(&dst[(size_t)(j * 16 + lr) * Sc + s]) = o;
      }
    }
  }
}

// ---------------------------------------------------------------- kernel 3: KTV + ksum partials (T-layout inputs)
// KTV[a][v] = sum_s phiKT[a][s] * VT[v][s];  block = (1024-s chunk, bh)
__global__ __launch_bounds__(256) void ktv_part_k(const ushort* __restrict__ KT,
                                                  const ushort* __restrict__ VT,
                                                  float* __restrict__ KTVp,
                                                  float* __restrict__ ksump) {
  __shared__ __align__(16) ushort Ks[64 * 128];
  __shared__ __align__(16) ushort Vs[64 * 128];
  __shared__ float red[64][65];
  const int t = threadIdx.x, chunk = blockIdx.x, bh = blockIdx.y;
  const int wave = t >> 6, lane = t & 63, lr = lane & 15, kg = lane >> 4;
  const size_t hb = (size_t)bh * 64 * Sc;
  const int s0 = chunk * 1024;

  f32x4 acc[4][4];
#pragma unroll
  for (int i = 0; i < 4; i++)
#pragma unroll
    for (int j = 0; j < 4; j++) acc[i][j] = (f32x4){0.f, 0.f, 0.f, 0.f};
  float ks_acc = 0.f;

  // staging: issue is in {0..3}: lds elem = is*2048 + t*8; row = is*16 + (t>>4); c' = t&15
  const int srl = t >> 4;                       // row low
  const int scc = (t & 15) ^ ((t >> 4) & 7);    // global chunk (row&7 == (t>>4)&7)
  const int wb  = (t >> 6) * 512;
  // read-side: c_read = wave*4 + kg; c' = c_read ^ (lr&7)
  const int cR = ((wave * 4 + kg) ^ (lr & 7)) * 8;

  for (int st = 0; st < 8; ++st) {
    const int sb = s0 + st * 128;
    __syncthreads();
#pragma unroll
    for (int is = 0; is < 4; ++is) {
      const int row = is * 16 + srl;
      gld_lds16(KT + hb + (size_t)row * Sc + sb + scc * 8, Ks + is * 2048 + wb);
      gld_lds16(VT + hb + (size_t)row * Sc + sb + scc * 8, Vs + is * 2048 + wb);
    }
    __syncthreads();
    {
      bf16x8 af[4], bfr[4];
#pragma unroll
      for (int i = 0; i < 4; i++)
        af[i] = *reinterpret_cast<const bf16x8*>(&Ks[(i * 16 + lr) * 128 + cR]);
#pragma unroll
      for (int j = 0; j < 4; j++)
        bfr[j] = *reinterpret_cast<const bf16x8*>(&Vs[(j * 16 + lr) * 128 + cR]);
#pragma unroll
      for (int i = 0; i < 4; i++)
#pragma unroll
        for (int j = 0; j < 4; j++)
          acc[i][j] = __builtin_amdgcn_mfma_f32_16x16x32_bf16(af[i], bfr[j], acc[i][j], 0, 0, 0);
    }
    if (t < 64) {  // row t is a-index; swizzle is a within-row permutation -> plain sum ok
      float s = 0.f;
      for (int e = 0; e < 128; e++) s += bf2f(Ks[t * 128 + e]);
      ks_acc += s;
    }
  }

  __syncthreads();
  for (int li = t; li < 64 * 65; li += 256) (&red[0][0])[li] = 0.f;
  __syncthreads();
  for (int w = 0; w < 4; w++) {
    if (wave == w) {
#pragma unroll
      for (int i = 0; i < 4; i++)
#pragma unroll
        for (int j = 0; j < 4; j++)
#pragma unroll
          for (int r = 0; r < 4; r++)
            red[i * 16 + kg * 4 + r][j * 16 + lr] += acc[i][j][r];
    }
    __syncthreads();
  }
  float* outp = KTVp + ((size_t)bh * 8 + chunk) * 4096;
  for (int li = t; li < 4096; li += 256) outp[li] = red[li >> 6][li & 63];
  if (t < 64) ksump[((size_t)bh * 8 + chunk) * 64 + t] = ks_acc;
}

// ---------------------------------------------------------------- kernel 3b: reduce partials
__global__ __launch_bounds__(256) void ktv_red_k(const float* __restrict__ KTVp,
                                                 const float* __restrict__ ksump,
                                                 float* __restrict__ KTV,
                                                 float* __restrict__ ksum) {
  const int bh = blockIdx.x, t = threadIdx.x;
  for (int li = t; li < 4096; li += 256) {
    float s = 0.f;
    for (int c = 0; c < 8; c++) s += KTVp[((size_t)bh * 8 + c) * 4096 + li];
    KTV[(size_t)bh * 4096 + li] = s;
  }
  if (t < 64) {
    float s = 0.f;
    for (int c = 0; c < 8; c++) s += ksump[((size_t)bh * 8 + c) * 64 + t];
    ksum[bh * 64 + t] = s;
  }
}

// ---------------------------------------------------------------- kernel 4: numerator + denominator + output
__global__ __launch_bounds__(256) void out_k(const ushort* __restrict__ Qphi,
                                             const float* __restrict__ KTV,
                                             const float* __restrict__ ksum,
                                             float* __restrict__ out) {
  __shared__ ushort Qs[256][72];
  __shared__ ushort BT[64][72];     // KTV^T in bf16: BT[v][a]
  __shared__ float  den[256];
  __shared__ float  kss[64];
  const int t = threadIdx.x;
  const int bh = blockIdx.y, s0 = blockIdx.x * 256;
  const ushort* qb = Qphi + (size_t)bh * Sc * 64 + (size_t)s0 * 64;

#pragma unroll
  for (int i = 0; i < 8; i++) {
    int li = i * 256 + t;
    int r = li >> 3, c8 = li & 7;
    *reinterpret_cast<uint4*>(&Qs[r][c8 * 8]) = *reinterpret_cast<const uint4*>(&qb[li * 8]);
  }
  for (int li = t; li < 4096; li += 256) {
    int a = li >> 6, v = li & 63;
    BT[v][a] = f2bf(KTV[(size_t)bh * 4096 + li]);
  }
  if (t < 64) kss[t] = ksum[bh * 64 + t];
  __syncthreads();

  {
    float d = 0.f;
    for (int a = 0; a < 64; a++) d += bf2f(Qs[t][a]) * kss[a];
    den[t] = d + EPSc;
  }
  __syncthreads();

  const int wave = t >> 6, lane = t & 63, lr = lane & 15, kg = lane >> 4;
  f32x4 acc[4][4];
#pragma unroll
  for (int i = 0; i < 4; i++)
#pragma unroll
    for (int j = 0; j < 4; j++) acc[i][j] = (f32x4){0.f, 0.f, 0.f, 0.f};

#pragma unroll
  for (int ks = 0; ks < 64; ks += 32) {
    bf16x8 af[4], bfr[4];
#pragma unroll
    for (int i = 0; i < 4; i++)
      af[i] = *reinterpret_cast<const bf16x8*>(&Qs[wave * 64 + i * 16 + lr][ks + kg * 8]);
#pragma unroll
    for (int j = 0; j < 4; j++)
      bfr[j] = *reinterpret_cast<const bf16x8*>(&BT[j * 16 + lr][ks + kg * 8]);
#pragma unroll
    for (int i = 0; i < 4; i++)
#pragma unroll
      for (int j = 0; j < 4; j++)
        acc[i][j] = __builtin_amdgcn_mfma_f32_16x16x32_bf16(af[i], bfr[j], acc[i][j], 0, 0, 0);
  }

  const int bq = bh >> 4, h = bh & 15;
#pragma unroll
  for (int i = 0; i < 4; i++) {
#pragma unroll
    for (int j = 0; j < 4; j++) {
#pragma unroll
      for (int r = 0; r < 4; r++) {
        int row = wave * 64 + i * 16 + kg * 4 + r;
        int s = s0 + row;
        int v = j * 16 + lr;
        out[((size_t)bq * Sc + s) * 1024 + h * 64 + v] = acc[i][j][r] / den[row];
      }
    }
  }
}

// ---------------------------------------------------------------- launch
extern "C" void kernel_launch(void* const* d_in, const int* in_sizes, int n_in,
                              void* d_out, int out_size, void* d_ws, size_t ws_size,
                              hipStream_t stream) {
  const float* x     = (const float*)d_in[0];
  const float* W_qkv = (const float*)d_in[1];
  const float* b_qkv = (const float*)d_in[2];
  const float* W_p   = (const float*)d_in[3];
  const float* b_p   = (const float*)d_in[4];
  float* out = (float*)d_out;

  size_t off = 0;
  auto carve = [&](size_t bytes) -> void* {
    void* p = (char*)d_ws + off;
    off += (bytes + 255) & ~(size_t)255;
    return p;
  };
  const size_t headElems = (size_t)BHc * Sc * 64;           // 33,554,432
  ushort* xb    = (ushort*)carve((size_t)Mc * Dc * 2);      // 64 MB
  ushort* Qb    = (ushort*)carve(headElems * 2);            // phiQ  [B,H,S,64]
  ushort* KTb   = (ushort*)carve(headElems * 2);            // phiK  [B,H,64,S]
  ushort* VTb   = (ushort*)carve(headElems * 2);            // V     [B,H,64,S]
  ushort* W3b   = (ushort*)carve((size_t)N3c * Dc * 2);
  float*  bias3 = (float*)carve((size_t)N3c * 4);
  float*  KTVp  = (float*)carve((size_t)BHc * 8 * 4096 * 4);
  float*  ksmp  = (float*)carve((size_t)BHc * 8 * 64 * 4);
  float*  KTV   = (float*)carve((size_t)BHc * 4096 * 4);
  float*  ksum  = (float*)carve((size_t)BHc * 64 * 4);
  (void)ws_size; (void)n_in; (void)in_sizes; (void)out_size;

  cvt_bf16_k<<<2048, 256, 0, stream>>>(x, xb, Mc * Dc / 4);
  fold_k<<<48, 256, 0, stream>>>(W_qkv, W_p, b_qkv, b_p, W3b, bias3);
  gemm_pipe_k<<<(Mc / 256) * (N3c / 256), 512, 0, stream>>>(xb, W3b, bias3, Qb, KTb, VTb);
  ktv_part_k<<<dim3(8, BHc), 256, 0, stream>>>(KTb, VTb, KTVp, ksmp);
  ktv_red_k<<<BHc, 256, 0, stream>>>(KTVp, ksmp, KTV, ksum);
  out_k<<<dim3(Sc / 256, BHc), 256, 0, stream>>>(Qb, KTV, ksum, out);
}